// Round 2
// baseline (6911.786 us; speedup 1.0000x reference)
//
#include <hip/hip_runtime.h>
#include <stdint.h>

// Problem constants (B=1)
#define H_  12
#define DH_ 64
#define D_  768
#define TD_ 2304      // 3*D
#define E_  128
#define L_  256
#define M_  (E_*L_)   // 32768 rows
#define KDIM_ 768

typedef __bf16 bf16x8 __attribute__((ext_vector_type(8)));
typedef float  f32x4  __attribute__((ext_vector_type(4)));

__device__ __forceinline__ float b2f(unsigned short u) {
    return __uint_as_float(((unsigned int)u) << 16);
}
__device__ __forceinline__ unsigned short f2b(float f) {
    unsigned int u = __float_as_uint(f);
    u += 0x7fffu + ((u >> 16) & 1u);   // RNE
    return (unsigned short)(u >> 16);
}

union frag_u { unsigned short u[8]; bf16x8 v; };

// ---------------------------------------------------------------------------
// fp32 -> bf16 elementwise (for weight panels)
// ---------------------------------------------------------------------------
__global__ __launch_bounds__(256) void cvt_f32_bf16(
    const float* __restrict__ src, unsigned short* __restrict__ dst, int n)
{
    int i = blockIdx.x * 256 + threadIdx.x;
    if (i < n) dst[i] = f2b(src[i]);
}

// ---------------------------------------------------------------------------
// C[M,2304](bf16) = A[M,768](fp32) @ Wb[2304,768](bf16)^T + bias(fp32)
// Wave computes 32x32 (2x2 of 16x16x32 MFMA tiles); block = 4 waves = 64x64.
// A-frag: A[m=lane&15][k=quad*8+j]; B-frag same addressing on W rows (B^T).
// C/D: col=lane&15, row=quad*4+reg  (verified layout, m89/m91).
// ---------------------------------------------------------------------------
__global__ __launch_bounds__(256) void gemm_bt(
    const float* __restrict__ A,
    const unsigned short* __restrict__ Wb,
    const float* __restrict__ bias,
    unsigned short* __restrict__ C)
{
    int lane = threadIdx.x & 63;
    int w    = threadIdx.x >> 6;
    int m0 = blockIdx.y * 64 + (w >> 1) * 32;
    int n0 = blockIdx.x * 64 + (w & 1) * 32;
    int l15  = lane & 15;
    int quad = lane >> 4;

    const float* a0p = A + (size_t)(m0 + l15) * KDIM_ + quad * 8;
    const float* a1p = a0p + (size_t)16 * KDIM_;
    const unsigned short* b0p = Wb + (size_t)(n0 + l15) * KDIM_ + quad * 8;
    const unsigned short* b1p = b0p + (size_t)16 * KDIM_;

    f32x4 acc00 = {0.f,0.f,0.f,0.f};
    f32x4 acc01 = acc00, acc10 = acc00, acc11 = acc00;

    for (int kb = 0; kb < KDIM_ / 32; kb++) {
        f32x4 a0lo = *(const f32x4*)(a0p);
        f32x4 a0hi = *(const f32x4*)(a0p + 4);
        f32x4 a1lo = *(const f32x4*)(a1p);
        f32x4 a1hi = *(const f32x4*)(a1p + 4);
        frag_u a0, a1;
        #pragma unroll
        for (int j = 0; j < 4; j++) {
            a0.u[j]   = f2b(a0lo[j]);  a0.u[4+j] = f2b(a0hi[j]);
            a1.u[j]   = f2b(a1lo[j]);  a1.u[4+j] = f2b(a1hi[j]);
        }
        bf16x8 b0 = *(const bf16x8*)(const void*)b0p;
        bf16x8 b1 = *(const bf16x8*)(const void*)b1p;
        a0p += 32; a1p += 32; b0p += 32; b1p += 32;
        acc00 = __builtin_amdgcn_mfma_f32_16x16x32_bf16(a0.v, b0, acc00, 0, 0, 0);
        acc01 = __builtin_amdgcn_mfma_f32_16x16x32_bf16(a0.v, b1, acc01, 0, 0, 0);
        acc10 = __builtin_amdgcn_mfma_f32_16x16x32_bf16(a1.v, b0, acc10, 0, 0, 0);
        acc11 = __builtin_amdgcn_mfma_f32_16x16x32_bf16(a1.v, b1, acc11, 0, 0, 0);
    }

    int colA = n0 + l15;
    int colB = n0 + 16 + l15;
    float bia = bias[colA];
    float bib = bias[colB];
    int rbase = m0 + quad * 4;
    for (int r = 0; r < 4; r++) {
        int row0 = rbase + r;
        int row1 = row0 + 16;
        C[(size_t)row0 * TD_ + colA] = f2b(acc00[r] + bia);
        C[(size_t)row0 * TD_ + colB] = f2b(acc01[r] + bib);
        C[(size_t)row1 * TD_ + colA] = f2b(acc10[r] + bia);
        C[(size_t)row1 * TD_ + colB] = f2b(acc11[r] + bib);
    }
}

// ---------------------------------------------------------------------------
// Attention over n keys (=n queries), one (outer,h) per block, 4 waves.
// mode 0: row attn, outer=e, i/j over L, qkv row stride TD_
// mode 1: col attn, outer=l, i/j over E, qkv row stride L_*TD_
// ---------------------------------------------------------------------------
__global__ __launch_bounds__(256) void attn_kernel(
    const unsigned short* __restrict__ qkv,
    unsigned short* __restrict__ attnout,
    const int* __restrict__ mask,
    int mode)
{
    __shared__ unsigned short Ks[256 * 64];  // 32 KB
    __shared__ float Ps[4 * 256];            // per-wave unnormalized probs
    __shared__ float negs[256];

    int tid  = threadIdx.x;
    int lane = tid & 63;
    int w    = tid >> 6;
    int h     = blockIdx.x % H_;
    int outer = blockIdx.x / H_;

    int n; size_t base, stride, obase, ostride; int mbase, mstride;
    if (mode == 0) {
        n = L_;  base = (size_t)outer * L_ * TD_; stride = TD_;
        obase = (size_t)outer * L_ * D_; ostride = D_;
        mbase = outer * L_; mstride = 1;
    } else {
        n = E_;  base = (size_t)outer * TD_; stride = (size_t)L_ * TD_;
        obase = (size_t)outer * D_; ostride = (size_t)L_ * D_;
        mbase = outer; mstride = L_;
    }
    const unsigned short* Qg = qkv + base + h * DH_;
    const unsigned short* Kg = Qg + D_;
    const unsigned short* Vg = Qg + 2 * D_;

    for (int idx = tid; idx < n * DH_; idx += 256) {
        int j = idx >> 6, d = idx & 63;
        Ks[idx] = Kg[(size_t)j * stride + d];
    }
    for (int j = tid; j < n; j += 256)
        negs[j] = mask[mbase + j * mstride] ? -10000.0f : 0.0f;
    __syncthreads();

    int ngrp = n >> 6;   // key groups of 64 (4 row / 2 col)
    int nq   = n >> 2;   // queries per wave
    const unsigned int* Ks32 = (const unsigned int*)Ks;

    for (int qi = 0; qi < nq; qi++) {
        int i = w + qi * 4;
        float qreg = b2f(Qg[(size_t)i * stride + lane]) * 0.125f;  // DH^-0.5

        float s[4];
        for (int g = 0; g < ngrp; g++) {
            int j = g * 64 + lane;
            float acc0 = 0.f, acc1 = 0.f;
            const unsigned int* krow = Ks32 + j * 32;
            #pragma unroll
            for (int p0 = 0; p0 < 32; p0++) {
                int pp = (p0 + lane) & 31;           // rotate start: kills bank conflicts
                unsigned int kk = krow[pp];          // 2 bf16
                float k0 = __uint_as_float(kk << 16);
                float k1 = __uint_as_float(kk & 0xffff0000u);
                float q0 = __shfl(qreg, pp * 2);
                float q1 = __shfl(qreg, pp * 2 + 1);
                acc0 = fmaf(q0, k0, acc0);
                acc1 = fmaf(q1, k1, acc1);
            }
            s[g] = acc0 + acc1 + negs[j];
        }
        float mx = s[0];
        for (int g = 1; g < ngrp; g++) mx = fmaxf(mx, s[g]);
        for (int off = 32; off; off >>= 1) mx = fmaxf(mx, __shfl_xor(mx, off));
        float sum = 0.f;
        for (int g = 0; g < ngrp; g++) { float p = __expf(s[g] - mx); s[g] = p; sum += p; }
        for (int off = 32; off; off >>= 1) sum += __shfl_xor(sum, off);
        for (int g = 0; g < ngrp; g++) Ps[w * 256 + g * 64 + lane] = s[g];
        float inv = 1.0f / sum;

        float o = 0.f;
        const float* pw = Ps + w * 256;
        for (int j = 0; j < n; j++) {
            float v = b2f(Vg[(size_t)j * stride + lane]);
            o = fmaf(pw[j], v, o);       // pw[j]: LDS broadcast (free)
        }
        attnout[obase + (size_t)i * ostride + h * DH_ + lane] = f2b(o * inv);
    }
}

// ---------------------------------------------------------------------------
// out(fp32) = LayerNorm(x(fp32) + r(bf16)) * g + beta  — one wave per row
// ---------------------------------------------------------------------------
__global__ __launch_bounds__(256) void add_ln(
    const float* __restrict__ x,
    const unsigned short* __restrict__ r,
    const float* __restrict__ g,
    const float* __restrict__ bta,
    float* __restrict__ out)
{
    int row  = blockIdx.x * 4 + (threadIdx.x >> 6);
    int lane = threadIdx.x & 63;
    size_t off = (size_t)row * D_;
    float v[12];
    float sum = 0.f;
    #pragma unroll
    for (int j = 0; j < 12; j++) {
        int c = j * 64 + lane;
        v[j] = x[off + c] + b2f(r[off + c]);
        sum += v[j];
    }
    for (int o = 32; o; o >>= 1) sum += __shfl_xor(sum, o);
    float mu = sum * (1.0f / 768.0f);
    float s2 = 0.f;
    #pragma unroll
    for (int j = 0; j < 12; j++) { float d = v[j] - mu; s2 = fmaf(d, d, s2); }
    for (int o = 32; o; o >>= 1) s2 += __shfl_xor(s2, o);
    float rs = rsqrtf(s2 * (1.0f / 768.0f) + 1e-5f);
    #pragma unroll
    for (int j = 0; j < 12; j++) {
        int c = j * 64 + lane;
        out[off + c] = (v[j] - mu) * rs * g[c] + bta[c];
    }
}

// ---------------------------------------------------------------------------
extern "C" void kernel_launch(void* const* d_in, const int* in_sizes, int n_in,
                              void* d_out, int out_size, void* d_ws, size_t ws_size,
                              hipStream_t stream)
{
    const float* x     = (const float*)d_in[0];
    const float* w_row = (const float*)d_in[1];
    const float* b_row = (const float*)d_in[2];
    const float* w_col = (const float*)d_in[3];
    const float* b_col = (const float*)d_in[4];
    const float* g1    = (const float*)d_in[5];
    const float* be1   = (const float*)d_in[6];
    const float* g2    = (const float*)d_in[7];
    const float* be2   = (const float*)d_in[8];
    const int*   mask  = (const int*)d_in[9];
    float* out = (float*)d_out;

    char* ws = (char*)d_ws;
    size_t o = 0;
    unsigned short* qkv  = (unsigned short*)(ws + o); o += (size_t)M_ * TD_ * 2;  // 151 MB
    unsigned short* attn = (unsigned short*)(ws + o); o += (size_t)M_ * D_ * 2;   // 50 MB
    float*          out1 = (float*)         (ws + o); o += (size_t)M_ * D_ * 4;   // 100 MB
    unsigned short* wbr  = (unsigned short*)(ws + o); o += (size_t)TD_ * KDIM_ * 2; // 3.5 MB
    unsigned short* wbc  = (unsigned short*)(ws + o);                              // 3.5 MB

    int wn = TD_ * KDIM_;
    cvt_f32_bf16<<<(wn + 255) / 256, 256, 0, stream>>>(w_row, wbr, wn);
    cvt_f32_bf16<<<(wn + 255) / 256, 256, 0, stream>>>(w_col, wbc, wn);

    dim3 gg(TD_ / 64, M_ / 64);   // 36 x 512 blocks

    // ---- row attention ----
    gemm_bt<<<gg, 256, 0, stream>>>(x, wbr, b_row, qkv);
    attn_kernel<<<E_ * H_, 256, 0, stream>>>(qkv, attn, mask, 0);
    add_ln<<<M_ / 4, 256, 0, stream>>>(x, attn, g1, be1, out1);

    // ---- column attention ----
    gemm_bt<<<gg, 256, 0, stream>>>(out1, wbc, b_col, qkv);
    attn_kernel<<<L_ * H_, 256, 0, stream>>>(qkv, attn, mask, 1);
    add_ln<<<M_ / 4, 256, 0, stream>>>(out1, attn, g2, be2, out);
}

// Round 3
// 2710.275 us; speedup vs baseline: 2.5502x; 2.5502x over previous
//
#include <hip/hip_runtime.h>
#include <stdint.h>

// Problem constants (B=1)
#define H_  12
#define DH_ 64
#define D_  768
#define TD_ 2304      // 3*D
#define E_  128
#define L_  256
#define M_  (E_*L_)   // 32768 rows
#define KDIM_ 768

typedef __bf16 bf16x8 __attribute__((ext_vector_type(8)));
typedef float  f32x4  __attribute__((ext_vector_type(4)));

__device__ __forceinline__ float b2f(unsigned short u) {
    return __uint_as_float(((unsigned int)u) << 16);
}
__device__ __forceinline__ unsigned short f2b(float f) {
    unsigned int u = __float_as_uint(f);
    u += 0x7fffu + ((u >> 16) & 1u);   // RNE
    return (unsigned short)(u >> 16);
}

union frag_u { unsigned short u[8]; bf16x8 v; };

// ---------------------------------------------------------------------------
// fp32 -> bf16 elementwise (weight panels)
// ---------------------------------------------------------------------------
__global__ __launch_bounds__(256) void cvt_f32_bf16(
    const float* __restrict__ src, unsigned short* __restrict__ dst, int n)
{
    int i = blockIdx.x * 256 + threadIdx.x;
    if (i < n) dst[i] = f2b(src[i]);
}

// ---------------------------------------------------------------------------
// C[M,2304](bf16) = A[M,768](fp32) @ Wb[2304,768](bf16)^T + bias(fp32)
// ---------------------------------------------------------------------------
__global__ __launch_bounds__(256) void gemm_bt(
    const float* __restrict__ A,
    const unsigned short* __restrict__ Wb,
    const float* __restrict__ bias,
    unsigned short* __restrict__ C)
{
    int lane = threadIdx.x & 63;
    int w    = threadIdx.x >> 6;
    int m0 = blockIdx.y * 64 + (w >> 1) * 32;
    int n0 = blockIdx.x * 64 + (w & 1) * 32;
    int l15  = lane & 15;
    int quad = lane >> 4;

    const float* a0p = A + (size_t)(m0 + l15) * KDIM_ + quad * 8;
    const float* a1p = a0p + (size_t)16 * KDIM_;
    const unsigned short* b0p = Wb + (size_t)(n0 + l15) * KDIM_ + quad * 8;
    const unsigned short* b1p = b0p + (size_t)16 * KDIM_;

    f32x4 acc00 = {0.f,0.f,0.f,0.f};
    f32x4 acc01 = acc00, acc10 = acc00, acc11 = acc00;

    for (int kb = 0; kb < KDIM_ / 32; kb++) {
        f32x4 a0lo = *(const f32x4*)(a0p);
        f32x4 a0hi = *(const f32x4*)(a0p + 4);
        f32x4 a1lo = *(const f32x4*)(a1p);
        f32x4 a1hi = *(const f32x4*)(a1p + 4);
        frag_u a0, a1;
        #pragma unroll
        for (int j = 0; j < 4; j++) {
            a0.u[j]   = f2b(a0lo[j]);  a0.u[4+j] = f2b(a0hi[j]);
            a1.u[j]   = f2b(a1lo[j]);  a1.u[4+j] = f2b(a1hi[j]);
        }
        bf16x8 b0 = *(const bf16x8*)(const void*)b0p;
        bf16x8 b1 = *(const bf16x8*)(const void*)b1p;
        a0p += 32; a1p += 32; b0p += 32; b1p += 32;
        acc00 = __builtin_amdgcn_mfma_f32_16x16x32_bf16(a0.v, b0, acc00, 0, 0, 0);
        acc01 = __builtin_amdgcn_mfma_f32_16x16x32_bf16(a0.v, b1, acc01, 0, 0, 0);
        acc10 = __builtin_amdgcn_mfma_f32_16x16x32_bf16(a1.v, b0, acc10, 0, 0, 0);
        acc11 = __builtin_amdgcn_mfma_f32_16x16x32_bf16(a1.v, b1, acc11, 0, 0, 0);
    }

    int colA = n0 + l15;
    int colB = n0 + 16 + l15;
    float bia = bias[colA];
    float bib = bias[colB];
    int rbase = m0 + quad * 4;
    for (int r = 0; r < 4; r++) {
        int row0 = rbase + r;
        int row1 = row0 + 16;
        C[(size_t)row0 * TD_ + colA] = f2b(acc00[r] + bia);
        C[(size_t)row0 * TD_ + colB] = f2b(acc01[r] + bib);
        C[(size_t)row1 * TD_ + colA] = f2b(acc10[r] + bia);
        C[(size_t)row1 * TD_ + colB] = f2b(acc11[r] + bib);
    }
}

// ---------------------------------------------------------------------------
// MFMA attention. One (outer,h) per block, 4 waves, 256 threads.
// MODE 0: row attn (n=256 over L, qkv row stride TD_)
// MODE 1: col attn (n=128 over E, qkv row stride L_*TD_)
// Wave owns N/64 m-tiles of 16 queries. S strip in C-layout regs; softmax
// via 4x shfl_xor (row = quad*4+r in-lane). P -> LDS strip (A-layout),
// V^T staged once per block in MFMA-tile order (conflict-free b128).
// ---------------------------------------------------------------------------
template<int MODE>
__global__ __launch_bounds__(256) void attn_mfma(
    const unsigned short* __restrict__ qkv,
    unsigned short* __restrict__ attnout,
    const int* __restrict__ mask)
{
    constexpr int N  = (MODE == 0) ? L_ : E_;   // keys (= queries)
    constexpr int NT = N / 16;                  // S col-tiles
    constexpr int KS = N / 32;                  // PV k-steps
    constexpr int HALVES = N / 128;             // P-strip passes (128 keys each)
    constexpr int MT = N / 64;                  // m-tiles per wave

    __shared__ unsigned short VtS[64 * N];      // V^T in MFMA-tile order
    __shared__ unsigned short Ps[4][16][136];   // per-wave P strip (16B-aligned rows)

    const int tid  = threadIdx.x;
    const int lane = tid & 63;
    const int w    = tid >> 6;
    const int quad = lane >> 4;
    const int l15  = lane & 15;
    const int hh    = blockIdx.x % H_;
    const int outer = blockIdx.x / H_;

    size_t base, stride, obase, ostride; int mbase, mstride;
    if (MODE == 0) {
        stride = TD_;             base  = (size_t)outer * L_ * TD_;
        obase  = (size_t)outer * L_ * D_;  ostride = D_;
        mbase  = outer * L_;      mstride = 1;
    } else {
        stride = (size_t)L_ * TD_; base = (size_t)outer * TD_;
        obase  = (size_t)outer * D_;       ostride = (size_t)L_ * D_;
        mbase  = outer;           mstride = L_;
    }
    const unsigned short* Qg = qkv + base + hh * DH_;
    const unsigned short* Kg = Qg + D_;
    const unsigned short* Vg = Qg + 2 * D_;

    // ---- stage V^T tiles: VtS[(tile*64+lane)*8+jj] = V[kt*32+q*8+jj][dt*16+f]
    for (int c = tid; c < 4 * KS * 64; c += 256) {
        int tile = c >> 6, lc = c & 63;
        int qd = lc >> 4, fl = lc & 15;
        int dt = tile / KS, kt = tile % KS;
        int jb = kt * 32 + qd * 8;
        int d  = dt * 16 + fl;
        frag_u tmp;
        #pragma unroll
        for (int jj = 0; jj < 8; jj++)
            tmp.u[jj] = Vg[(size_t)(jb + jj) * stride + d];
        *(bf16x8*)(void*)&VtS[c * 8] = tmp.v;
    }

    // ---- mask -> registers (neg per col-tile)
    float negreg[NT];
    #pragma unroll
    for (int nt = 0; nt < NT; nt++)
        negreg[nt] = mask[mbase + (nt * 16 + l15) * mstride] ? -10000.0f : 0.0f;

    __syncthreads();

    for (int mt = 0; mt < MT; mt++) {
        int m0 = (w * MT + mt) * 16;

        bf16x8 aq0 = *(const bf16x8*)(const void*)&Qg[(size_t)(m0 + l15) * stride + quad * 8];
        bf16x8 aq1 = *(const bf16x8*)(const void*)&Qg[(size_t)(m0 + l15) * stride + 32 + quad * 8];

        f32x4 sc[NT];
        #pragma unroll
        for (int nt = 0; nt < NT; nt++) sc[nt] = (f32x4){0.f,0.f,0.f,0.f};
        #pragma unroll
        for (int nt = 0; nt < NT; nt++) {
            bf16x8 bk0 = *(const bf16x8*)(const void*)&Kg[(size_t)(nt*16 + l15) * stride + quad * 8];
            bf16x8 bk1 = *(const bf16x8*)(const void*)&Kg[(size_t)(nt*16 + l15) * stride + 32 + quad * 8];
            sc[nt] = __builtin_amdgcn_mfma_f32_16x16x32_bf16(aq0, bk0, sc[nt], 0, 0, 0);
            sc[nt] = __builtin_amdgcn_mfma_f32_16x16x32_bf16(aq1, bk1, sc[nt], 0, 0, 0);
        }

        // ---- softmax over cols (rows live at quad*4+r)
        float mx[4] = {-1e30f, -1e30f, -1e30f, -1e30f};
        #pragma unroll
        for (int nt = 0; nt < NT; nt++)
            #pragma unroll
            for (int r = 0; r < 4; r++) {
                float s = sc[nt][r] * 0.125f + negreg[nt];
                sc[nt][r] = s;
                mx[r] = fmaxf(mx[r], s);
            }
        #pragma unroll
        for (int r = 0; r < 4; r++) {
            mx[r] = fmaxf(mx[r], __shfl_xor(mx[r], 1));
            mx[r] = fmaxf(mx[r], __shfl_xor(mx[r], 2));
            mx[r] = fmaxf(mx[r], __shfl_xor(mx[r], 4));
            mx[r] = fmaxf(mx[r], __shfl_xor(mx[r], 8));
        }
        float sum[4] = {0.f, 0.f, 0.f, 0.f};
        #pragma unroll
        for (int nt = 0; nt < NT; nt++)
            #pragma unroll
            for (int r = 0; r < 4; r++) {
                float p = __expf(sc[nt][r] - mx[r]);
                sc[nt][r] = p;
                sum[r] += p;
            }
        #pragma unroll
        for (int r = 0; r < 4; r++) {
            sum[r] += __shfl_xor(sum[r], 1);
            sum[r] += __shfl_xor(sum[r], 2);
            sum[r] += __shfl_xor(sum[r], 4);
            sum[r] += __shfl_xor(sum[r], 8);
        }

        // ---- PV: P via LDS strip (A-layout), V^T from LDS (B-layout)
        f32x4 oacc[4];
        #pragma unroll
        for (int dt = 0; dt < 4; dt++) oacc[dt] = (f32x4){0.f,0.f,0.f,0.f};

        #pragma unroll
        for (int h2 = 0; h2 < HALVES; h2++) {
            #pragma unroll
            for (int t = 0; t < 8; t++)
                #pragma unroll
                for (int r = 0; r < 4; r++)
                    Ps[w][quad * 4 + r][t * 16 + l15] = f2b(sc[h2 * 8 + t][r]);
            // same-wave DS ordering: writes complete before dependent reads (compiler waitcnt)
            #pragma unroll
            for (int kt = 0; kt < 4; kt++) {
                bf16x8 ap = *(const bf16x8*)(const void*)&Ps[w][l15][kt * 32 + quad * 8];
                #pragma unroll
                for (int dt = 0; dt < 4; dt++) {
                    bf16x8 bv = *(const bf16x8*)(const void*)
                        &VtS[((dt * KS + h2 * 4 + kt) * 64 + lane) * 8];
                    oacc[dt] = __builtin_amdgcn_mfma_f32_16x16x32_bf16(ap, bv, oacc[dt], 0, 0, 0);
                }
            }
        }

        // ---- epilogue: normalize rows (same lane mapping as softmax sums)
        float inv[4];
        #pragma unroll
        for (int r = 0; r < 4; r++) inv[r] = 1.0f / sum[r];
        #pragma unroll
        for (int dt = 0; dt < 4; dt++)
            #pragma unroll
            for (int r = 0; r < 4; r++) {
                size_t oaddr = obase + (size_t)(m0 + quad * 4 + r) * ostride
                             + hh * DH_ + dt * 16 + l15;
                attnout[oaddr] = f2b(oacc[dt][r] * inv[r]);
            }
    }
}

// ---------------------------------------------------------------------------
// out(fp32) = LayerNorm(x(fp32) + r(bf16)) * g + beta  — one wave per row
// ---------------------------------------------------------------------------
__global__ __launch_bounds__(256) void add_ln(
    const float* __restrict__ x,
    const unsigned short* __restrict__ r,
    const float* __restrict__ g,
    const float* __restrict__ bta,
    float* __restrict__ out)
{
    int row  = blockIdx.x * 4 + (threadIdx.x >> 6);
    int lane = threadIdx.x & 63;
    size_t off = (size_t)row * D_;
    float v[12];
    float sum = 0.f;
    #pragma unroll
    for (int j = 0; j < 12; j++) {
        int c = j * 64 + lane;
        v[j] = x[off + c] + b2f(r[off + c]);
        sum += v[j];
    }
    for (int o = 32; o; o >>= 1) sum += __shfl_xor(sum, o);
    float mu = sum * (1.0f / 768.0f);
    float s2 = 0.f;
    #pragma unroll
    for (int j = 0; j < 12; j++) { float d = v[j] - mu; s2 = fmaf(d, d, s2); }
    for (int o = 32; o; o >>= 1) s2 += __shfl_xor(s2, o);
    float rs = rsqrtf(s2 * (1.0f / 768.0f) + 1e-5f);
    #pragma unroll
    for (int j = 0; j < 12; j++) {
        int c = j * 64 + lane;
        out[off + c] = (v[j] - mu) * rs * g[c] + bta[c];
    }
}

// ---------------------------------------------------------------------------
extern "C" void kernel_launch(void* const* d_in, const int* in_sizes, int n_in,
                              void* d_out, int out_size, void* d_ws, size_t ws_size,
                              hipStream_t stream)
{
    const float* x     = (const float*)d_in[0];
    const float* w_row = (const float*)d_in[1];
    const float* b_row = (const float*)d_in[2];
    const float* w_col = (const float*)d_in[3];
    const float* b_col = (const float*)d_in[4];
    const float* g1    = (const float*)d_in[5];
    const float* be1   = (const float*)d_in[6];
    const float* g2    = (const float*)d_in[7];
    const float* be2   = (const float*)d_in[8];
    const int*   mask  = (const int*)d_in[9];
    float* out = (float*)d_out;

    char* ws = (char*)d_ws;
    size_t o = 0;
    unsigned short* qkv  = (unsigned short*)(ws + o); o += (size_t)M_ * TD_ * 2;  // 151 MB
    unsigned short* attn = (unsigned short*)(ws + o); o += (size_t)M_ * D_ * 2;   // 50 MB
    float*          out1 = (float*)         (ws + o); o += (size_t)M_ * D_ * 4;   // 100 MB
    unsigned short* wbr  = (unsigned short*)(ws + o); o += (size_t)TD_ * KDIM_ * 2; // 3.5 MB
    unsigned short* wbc  = (unsigned short*)(ws + o);                              // 3.5 MB

    int wn = TD_ * KDIM_;
    cvt_f32_bf16<<<(wn + 255) / 256, 256, 0, stream>>>(w_row, wbr, wn);
    cvt_f32_bf16<<<(wn + 255) / 256, 256, 0, stream>>>(w_col, wbc, wn);

    dim3 gg(TD_ / 64, M_ / 64);   // 36 x 512 blocks

    // ---- row attention ----
    gemm_bt<<<gg, 256, 0, stream>>>(x, wbr, b_row, qkv);
    attn_mfma<0><<<E_ * H_, 256, 0, stream>>>(qkv, attn, mask);
    add_ln<<<M_ / 4, 256, 0, stream>>>(x, attn, g1, be1, out1);

    // ---- column attention ----
    gemm_bt<<<gg, 256, 0, stream>>>(out1, wbc, b_col, qkv);
    attn_mfma<1><<<L_ * H_, 256, 0, stream>>>(qkv, attn, mask);
    add_ln<<<M_ / 4, 256, 0, stream>>>(out1, attn, g2, be2, out);
}

// Round 4
// 748.724 us; speedup vs baseline: 9.2314x; 3.6199x over previous
//
#include <hip/hip_runtime.h>
#include <stdint.h>

// Problem constants (B=1)
#define H_  12
#define DH_ 64
#define D_  768
#define TD_ 2304      // 3*D
#define E_  128
#define L_  256
#define M_  (E_*L_)   // 32768 rows
#define KDIM_ 768

typedef __bf16 bf16x8 __attribute__((ext_vector_type(8)));
typedef float  f32x4  __attribute__((ext_vector_type(4)));

__device__ __forceinline__ float b2f(unsigned short u) {
    return __uint_as_float(((unsigned int)u) << 16);
}
__device__ __forceinline__ unsigned short f2b(float f) {
    unsigned int u = __float_as_uint(f);
    u += 0x7fffu + ((u >> 16) & 1u);   // RNE
    return (unsigned short)(u >> 16);
}

union frag_u { unsigned short u[8]; bf16x8 v; };

#define GLOBAL_AS(p) ((const __attribute__((address_space(1))) void*)(p))
#define LDS_AS(p)    ((__attribute__((address_space(3))) void*)(p))

// ---------------------------------------------------------------------------
// fp32 -> bf16, 4 elements/thread (n % 4 == 0)
// ---------------------------------------------------------------------------
__global__ __launch_bounds__(256) void cvt4(
    const float4* __restrict__ src, ushort4* __restrict__ dst, int n4)
{
    int i = blockIdx.x * 256 + threadIdx.x;
    if (i < n4) {
        float4 f = src[i];
        ushort4 o;
        o.x = f2b(f.x); o.y = f2b(f.y); o.z = f2b(f.z); o.w = f2b(f.w);
        dst[i] = o;
    }
}

// ---------------------------------------------------------------------------
// C[M,2304](bf16) = A[M,768](bf16) @ Wb[2304,768](bf16)^T + bias(fp32)
// m97 structure: 128x128 tile, BK=32, global_load_lds width 16, 4 waves,
// 4x4 16x16x32 MFMA per wave. LDS chunk swizzle: element (R, colgroup c)
// stored at chunk R*4 + ((c + (R>>1)) & 3)  -> frag reads are 2-way (free).
// ---------------------------------------------------------------------------
__global__ __launch_bounds__(256) void gemm_lds(
    const unsigned short* __restrict__ A,
    const unsigned short* __restrict__ Wb,
    const float* __restrict__ bias,
    unsigned short* __restrict__ C)
{
    __shared__ unsigned short As[128 * 32];   // 8 KB
    __shared__ unsigned short Bs[128 * 32];   // 8 KB

    const int tid  = threadIdx.x;
    const int lane = tid & 63;
    const int w    = tid >> 6;
    const int l15  = lane & 15;
    const int quad = lane >> 4;

    const int m_blk = blockIdx.y * 128;
    const int n_blk = blockIdx.x * 128;
    const int wm = (w >> 1) * 64;
    const int wn = (w & 1) * 64;

    // staging: lane's LDS slot is fixed (chunk = s*256 + w*64 + lane); choose
    // the global colgroup that belongs in that slot: cc = ((lane&3)-(R>>1))&3,
    // which reduces to ((lane&3) - (lane>>3)) & 3 (wave/issue terms are %4==0).
    const int cc   = ((lane & 3) - (lane >> 3)) & 3;
    const int rloc = lane >> 2;
    const unsigned short* gA0 = A  + (size_t)(m_blk + w * 16 + rloc) * KDIM_ + cc * 8;
    const unsigned short* gA1 = gA0 + (size_t)64 * KDIM_;
    const unsigned short* gB0 = Wb + (size_t)(n_blk + w * 16 + rloc) * KDIM_ + cc * 8;
    const unsigned short* gB1 = gB0 + (size_t)64 * KDIM_;

    char* asb = (char*)As;
    char* bsb = (char*)Bs;
    char* dA0 = asb + w * 1024;
    char* dA1 = asb + 4096 + w * 1024;
    char* dB0 = bsb + w * 1024;
    char* dB1 = bsb + 4096 + w * 1024;

    // fragment read byte-offsets (constant over K loop)
    int offA[4], offB[4];
    #pragma unroll
    for (int t = 0; t < 4; t++) {
        int Ra = wm + t * 16 + l15;
        offA[t] = (Ra * 4 + ((quad + (Ra >> 1)) & 3)) * 16;
        int Rb = wn + t * 16 + l15;
        offB[t] = (Rb * 4 + ((quad + (Rb >> 1)) & 3)) * 16;
    }

    f32x4 acc[4][4];
    #pragma unroll
    for (int i = 0; i < 4; i++)
        #pragma unroll
        for (int j = 0; j < 4; j++) acc[i][j] = (f32x4){0.f, 0.f, 0.f, 0.f};

    for (int kb = 0; kb < KDIM_ / 32; kb++) {
        __builtin_amdgcn_global_load_lds(GLOBAL_AS(gA0), LDS_AS(dA0), 16, 0, 0);
        __builtin_amdgcn_global_load_lds(GLOBAL_AS(gA1), LDS_AS(dA1), 16, 0, 0);
        __builtin_amdgcn_global_load_lds(GLOBAL_AS(gB0), LDS_AS(dB0), 16, 0, 0);
        __builtin_amdgcn_global_load_lds(GLOBAL_AS(gB1), LDS_AS(dB1), 16, 0, 0);
        gA0 += 32; gA1 += 32; gB0 += 32; gB1 += 32;
        __syncthreads();   // drains vmcnt -> staged tiles visible

        bf16x8 af[4], bfr[4];
        #pragma unroll
        for (int t = 0; t < 4; t++) af[t]  = *(const bf16x8*)(const void*)(asb + offA[t]);
        #pragma unroll
        for (int t = 0; t < 4; t++) bfr[t] = *(const bf16x8*)(const void*)(bsb + offB[t]);
        #pragma unroll
        for (int mt = 0; mt < 4; mt++)
            #pragma unroll
            for (int nt = 0; nt < 4; nt++)
                acc[mt][nt] = __builtin_amdgcn_mfma_f32_16x16x32_bf16(
                    af[mt], bfr[nt], acc[mt][nt], 0, 0, 0);
        __syncthreads();   // before next staging overwrites tiles
    }

    // epilogue: C[row=quad*4+r][col=l15] per tile (verified layout)
    #pragma unroll
    for (int nt = 0; nt < 4; nt++) {
        int col = n_blk + wn + nt * 16 + l15;
        float bi = bias[col];
        #pragma unroll
        for (int mt = 0; mt < 4; mt++) {
            int rbase = m_blk + wm + mt * 16 + quad * 4;
            #pragma unroll
            for (int r = 0; r < 4; r++)
                C[(size_t)(rbase + r) * TD_ + col] = f2b(acc[mt][nt][r] + bi);
        }
    }
}

// ---------------------------------------------------------------------------
// MFMA attention. One (outer,h) per block, 4 waves, 256 threads.
// MODE 0: row attn (n=256 over L);  MODE 1: col attn (n=128 over E)
// ---------------------------------------------------------------------------
template<int MODE>
__global__ __launch_bounds__(256) void attn_mfma(
    const unsigned short* __restrict__ qkv,
    unsigned short* __restrict__ attnout,
    const int* __restrict__ mask)
{
    constexpr int N  = (MODE == 0) ? L_ : E_;
    constexpr int NT = N / 16;
    constexpr int KS = N / 32;
    constexpr int HALVES = N / 128;
    constexpr int MT = N / 64;

    __shared__ unsigned short VtS[64 * N];
    __shared__ unsigned short Ps[4][16][136];

    const int tid  = threadIdx.x;
    const int lane = tid & 63;
    const int w    = tid >> 6;
    const int quad = lane >> 4;
    const int l15  = lane & 15;
    const int hh    = blockIdx.x % H_;
    const int outer = blockIdx.x / H_;

    size_t base, stride, obase, ostride; int mbase, mstride;
    if (MODE == 0) {
        stride = TD_;              base = (size_t)outer * L_ * TD_;
        obase  = (size_t)outer * L_ * D_;  ostride = D_;
        mbase  = outer * L_;       mstride = 1;
    } else {
        stride = (size_t)L_ * TD_; base = (size_t)outer * TD_;
        obase  = (size_t)outer * D_;       ostride = (size_t)L_ * D_;
        mbase  = outer;            mstride = L_;
    }
    const unsigned short* Qg = qkv + base + hh * DH_;
    const unsigned short* Kg = Qg + D_;
    const unsigned short* Vg = Qg + 2 * D_;

    for (int c = tid; c < 4 * KS * 64; c += 256) {
        int tile = c >> 6, lc = c & 63;
        int qd = lc >> 4, fl = lc & 15;
        int dt = tile / KS, kt = tile % KS;
        int jb = kt * 32 + qd * 8;
        int d  = dt * 16 + fl;
        frag_u tmp;
        #pragma unroll
        for (int jj = 0; jj < 8; jj++)
            tmp.u[jj] = Vg[(size_t)(jb + jj) * stride + d];
        *(bf16x8*)(void*)&VtS[c * 8] = tmp.v;
    }

    float negreg[NT];
    #pragma unroll
    for (int nt = 0; nt < NT; nt++)
        negreg[nt] = mask[mbase + (nt * 16 + l15) * mstride] ? -10000.0f : 0.0f;

    __syncthreads();

    for (int mt = 0; mt < MT; mt++) {
        int m0 = (w * MT + mt) * 16;

        bf16x8 aq0 = *(const bf16x8*)(const void*)&Qg[(size_t)(m0 + l15) * stride + quad * 8];
        bf16x8 aq1 = *(const bf16x8*)(const void*)&Qg[(size_t)(m0 + l15) * stride + 32 + quad * 8];

        f32x4 sc[NT];
        #pragma unroll
        for (int nt = 0; nt < NT; nt++) sc[nt] = (f32x4){0.f,0.f,0.f,0.f};
        #pragma unroll
        for (int nt = 0; nt < NT; nt++) {
            bf16x8 bk0 = *(const bf16x8*)(const void*)&Kg[(size_t)(nt*16 + l15) * stride + quad * 8];
            bf16x8 bk1 = *(const bf16x8*)(const void*)&Kg[(size_t)(nt*16 + l15) * stride + 32 + quad * 8];
            sc[nt] = __builtin_amdgcn_mfma_f32_16x16x32_bf16(aq0, bk0, sc[nt], 0, 0, 0);
            sc[nt] = __builtin_amdgcn_mfma_f32_16x16x32_bf16(aq1, bk1, sc[nt], 0, 0, 0);
        }

        float mx[4] = {-1e30f, -1e30f, -1e30f, -1e30f};
        #pragma unroll
        for (int nt = 0; nt < NT; nt++)
            #pragma unroll
            for (int r = 0; r < 4; r++) {
                float s = sc[nt][r] * 0.125f + negreg[nt];
                sc[nt][r] = s;
                mx[r] = fmaxf(mx[r], s);
            }
        #pragma unroll
        for (int r = 0; r < 4; r++) {
            mx[r] = fmaxf(mx[r], __shfl_xor(mx[r], 1));
            mx[r] = fmaxf(mx[r], __shfl_xor(mx[r], 2));
            mx[r] = fmaxf(mx[r], __shfl_xor(mx[r], 4));
            mx[r] = fmaxf(mx[r], __shfl_xor(mx[r], 8));
        }
        float sum[4] = {0.f, 0.f, 0.f, 0.f};
        #pragma unroll
        for (int nt = 0; nt < NT; nt++)
            #pragma unroll
            for (int r = 0; r < 4; r++) {
                float p = __expf(sc[nt][r] - mx[r]);
                sc[nt][r] = p;
                sum[r] += p;
            }
        #pragma unroll
        for (int r = 0; r < 4; r++) {
            sum[r] += __shfl_xor(sum[r], 1);
            sum[r] += __shfl_xor(sum[r], 2);
            sum[r] += __shfl_xor(sum[r], 4);
            sum[r] += __shfl_xor(sum[r], 8);
        }

        f32x4 oacc[4];
        #pragma unroll
        for (int dt = 0; dt < 4; dt++) oacc[dt] = (f32x4){0.f,0.f,0.f,0.f};

        #pragma unroll
        for (int h2 = 0; h2 < HALVES; h2++) {
            #pragma unroll
            for (int t = 0; t < 8; t++)
                #pragma unroll
                for (int r = 0; r < 4; r++)
                    Ps[w][quad * 4 + r][t * 16 + l15] = f2b(sc[h2 * 8 + t][r]);
            #pragma unroll
            for (int kt = 0; kt < 4; kt++) {
                bf16x8 ap = *(const bf16x8*)(const void*)&Ps[w][l15][kt * 32 + quad * 8];
                #pragma unroll
                for (int dt = 0; dt < 4; dt++) {
                    bf16x8 bv = *(const bf16x8*)(const void*)
                        &VtS[((dt * KS + h2 * 4 + kt) * 64 + lane) * 8];
                    oacc[dt] = __builtin_amdgcn_mfma_f32_16x16x32_bf16(ap, bv, oacc[dt], 0, 0, 0);
                }
            }
        }

        float inv[4];
        #pragma unroll
        for (int r = 0; r < 4; r++) inv[r] = 1.0f / sum[r];
        #pragma unroll
        for (int dt = 0; dt < 4; dt++)
            #pragma unroll
            for (int r = 0; r < 4; r++) {
                size_t oaddr = obase + (size_t)(m0 + quad * 4 + r) * ostride
                             + hh * DH_ + dt * 16 + l15;
                attnout[oaddr] = f2b(oacc[dt][r] * inv[r]);
            }
    }
}

// ---------------------------------------------------------------------------
// out = LayerNorm(x + r) * g + beta — one wave per row.
// XBF16: residual input dtype; OBF16: output dtype.
// ---------------------------------------------------------------------------
template<int XBF16, int OBF16>
__global__ __launch_bounds__(256) void add_ln(
    const void* __restrict__ xp,
    const unsigned short* __restrict__ r,
    const float* __restrict__ g,
    const float* __restrict__ bta,
    void* __restrict__ outp)
{
    int row  = blockIdx.x * 4 + (threadIdx.x >> 6);
    int lane = threadIdx.x & 63;
    size_t off = (size_t)row * D_;
    const float* xf = (const float*)xp;
    const unsigned short* xb = (const unsigned short*)xp;
    float v[12];
    float sum = 0.f;
    #pragma unroll
    for (int j = 0; j < 12; j++) {
        int c = j * 64 + lane;
        float xv = XBF16 ? b2f(xb[off + c]) : xf[off + c];
        v[j] = xv + b2f(r[off + c]);
        sum += v[j];
    }
    for (int o = 32; o; o >>= 1) sum += __shfl_xor(sum, o);
    float mu = sum * (1.0f / 768.0f);
    float s2 = 0.f;
    #pragma unroll
    for (int j = 0; j < 12; j++) { float d = v[j] - mu; s2 = fmaf(d, d, s2); }
    for (int o = 32; o; o >>= 1) s2 += __shfl_xor(s2, o);
    float rs = rsqrtf(s2 * (1.0f / 768.0f) + 1e-5f);
    #pragma unroll
    for (int j = 0; j < 12; j++) {
        int c = j * 64 + lane;
        float y = (v[j] - mu) * rs * g[c] + bta[c];
        if (OBF16) ((unsigned short*)outp)[off + c] = f2b(y);
        else       ((float*)outp)[off + c] = y;
    }
}

// ---------------------------------------------------------------------------
extern "C" void kernel_launch(void* const* d_in, const int* in_sizes, int n_in,
                              void* d_out, int out_size, void* d_ws, size_t ws_size,
                              hipStream_t stream)
{
    const float* x     = (const float*)d_in[0];
    const float* w_row = (const float*)d_in[1];
    const float* b_row = (const float*)d_in[2];
    const float* w_col = (const float*)d_in[3];
    const float* b_col = (const float*)d_in[4];
    const float* g1    = (const float*)d_in[5];
    const float* be1   = (const float*)d_in[6];
    const float* g2    = (const float*)d_in[7];
    const float* be2   = (const float*)d_in[8];
    const int*   mask  = (const int*)d_in[9];
    float* out = (float*)d_out;

    char* ws = (char*)d_ws;
    size_t o = 0;
    unsigned short* qkv   = (unsigned short*)(ws + o); o += (size_t)M_ * TD_ * 2;    // 151 MB
    unsigned short* attn  = (unsigned short*)(ws + o); o += (size_t)M_ * D_ * 2;     // 48 MB (aliases xb)
    unsigned short* out1b = (unsigned short*)(ws + o); o += (size_t)M_ * D_ * 2;     // 48 MB
    unsigned short* wbr   = (unsigned short*)(ws + o); o += (size_t)TD_ * KDIM_ * 2; // 3.4 MB
    unsigned short* wbc   = (unsigned short*)(ws + o);                               // 3.4 MB
    unsigned short* xb    = attn;   // safe alias: xb consumed by gemm1 before attn<0> writes

    int wn4 = TD_ * KDIM_ / 4;
    int xn4 = M_ * D_ / 4;
    cvt4<<<(wn4 + 255) / 256, 256, 0, stream>>>((const float4*)w_row, (ushort4*)wbr, wn4);
    cvt4<<<(wn4 + 255) / 256, 256, 0, stream>>>((const float4*)w_col, (ushort4*)wbc, wn4);
    cvt4<<<(xn4 + 255) / 256, 256, 0, stream>>>((const float4*)x, (ushort4*)xb, xn4);

    dim3 gg(TD_ / 128, M_ / 128);   // 18 x 256 blocks

    // ---- row attention ----
    gemm_lds<<<gg, 256, 0, stream>>>(xb, wbr, b_row, qkv);
    attn_mfma<0><<<E_ * H_, 256, 0, stream>>>(qkv, attn, mask);
    add_ln<0, 1><<<M_ / 4, 256, 0, stream>>>(x, attn, g1, be1, out1b);

    // ---- column attention ----
    gemm_lds<<<gg, 256, 0, stream>>>(out1b, wbc, b_col, qkv);
    attn_mfma<1><<<L_ * H_, 256, 0, stream>>>(qkv, attn, mask);
    add_ln<1, 0><<<M_ / 4, 256, 0, stream>>>(out1b, attn, g2, be2, out);
}